// Round 2
// baseline (188.171 us; speedup 1.0000x reference)
//
#include <hip/hip_runtime.h>
#include <math.h>

// ---------------------------------------------------------------------------
// AUV Fossen 6-DOF RK2 step, K independent 13-float states. Single fused
// kernel. R2 changes vs 42.7us kernel (hbm 23%, VALU 25%, occ 31% -> latency
// bound): (1) __launch_bounds__(256,8): VGPR already 64 -> 8 blocks/CU, the
// whole 2048-block grid resident in ONE generation; (2) wave-self-contained
// LDS regions (wave w owns float4 [208w,208w+208)) -> store-side barrier
// removed (wave-local lgkmcnt only), single __syncthreads total; (3) uniform
// structure flags: skip linDampFow matvec when all-zero and off-diag linDamp
// when diagonal (s_cmp + uniform branch, generically correct); (4) smi rows
// padded to 8 floats -> b128/b64 broadcast reads instead of 72x ds_read_b32.
// Memory floor: ~79MB traffic -> ~12.6us; VALU ~8us; target ~16us overlapped.
// ---------------------------------------------------------------------------

__device__ __forceinline__ float fast_rcp(float x) {
    float r = __builtin_amdgcn_rcpf(x);
    return r * (2.0f - x * r);        // 1 Newton step
}

__device__ __forceinline__ void fossen_dot(const float* __restrict__ X,
                                           const float* __restrict__ U,
                                           const float* __restrict__ smi,  // LDS [6][8] padded, broadcast
                                           const float* __restrict__ mTot, // uniform -> s_load
                                           const float* __restrict__ linDamp,
                                           const float* __restrict__ linDampFow,
                                           const float* __restrict__ qdiag,  // regs/sgpr [6]
                                           const float* __restrict__ lddiag, // regs/sgpr [6]
                                           const float* __restrict__ cgcb,   // regs/sgpr [6]
                                           float fgz, float fbz,
                                           bool ldDiag, bool ldfZero,
                                           float* __restrict__ xd)
{
    const float qx = X[3], qy = X[4], qz = X[5], qw = X[6];
    const float r00 = 1.f - 2.f*(qy*qy + qz*qz);
    const float r01 = 2.f*(qx*qy - qz*qw);
    const float r02 = 2.f*(qx*qz + qy*qw);
    const float r10 = 2.f*(qx*qy + qz*qw);
    const float r11 = 1.f - 2.f*(qx*qx + qz*qz);
    const float r12 = 2.f*(qy*qz - qx*qw);
    const float r20 = 2.f*(qx*qz - qy*qw);
    const float r21 = 2.f*(qy*qz + qx*qw);
    const float r22 = 1.f - 2.f*(qx*qx + qy*qy);

    const float v0 = X[7],  v1 = X[8],  v2 = X[9];
    const float v3 = X[10], v4 = X[11], v5 = X[12];

    xd[0] = r00*v0 + r01*v1 + r02*v2;
    xd[1] = r10*v0 + r11*v1 + r12*v2;
    xd[2] = r20*v0 + r21*v1 + r22*v2;
    xd[3] = 0.5f*(-qx*v3 - qy*v4 - qz*v5);
    xd[4] = 0.5f*( qw*v3 - qz*v4 + qy*v5);
    xd[5] = 0.5f*( qz*v3 + qw*v4 - qx*v5);
    xd[6] = 0.5f*(-qy*v3 + qx*v4 + qw*v5);

    const float v[6] = {v0, v1, v2, v3, v4, v5};

    // P = -Dv. Fast path: diagonal linDamp + zero linDampFow (uniform flags).
    float P[6];
#pragma unroll
    for (int i = 0; i < 6; ++i)
        P[i] = lddiag[i]*v[i] + qdiag[i]*fabsf(v[i])*v[i];
    if (!ldDiag) {
#pragma unroll
        for (int i = 0; i < 6; ++i) {
            float ld = 0.f;
#pragma unroll
            for (int j = 0; j < 6; ++j)
                if (j != i) ld += linDamp[i*6 + j] * v[j];
            P[i] += ld;
        }
    }
    if (!ldfZero) {
#pragma unroll
        for (int i = 0; i < 6; ++i) {
            float ldf = 0.f;
#pragma unroll
            for (int j = 0; j < 6; ++j) ldf += linDampFow[i*6 + j] * v[j];
            P[i] += v[i]*ldf;
        }
    }

    // Coriolis via mv = M v, then cross products (skew(a)b = a x b)
    float mv[6];
#pragma unroll
    for (int i = 0; i < 6; ++i) {
        float s = 0.f;
#pragma unroll
        for (int j = 0; j < 6; ++j) s += mTot[i*6 + j] * v[j];
        mv[i] = s;
    }
    float Cv[6];
    Cv[0] = -(mv[1]*v5 - mv[2]*v4);
    Cv[1] = -(mv[2]*v3 - mv[0]*v5);
    Cv[2] = -(mv[0]*v4 - mv[1]*v3);
    Cv[3] = -(mv[1]*v2 - mv[2]*v1) - (mv[4]*v5 - mv[5]*v4);
    Cv[4] = -(mv[2]*v0 - mv[0]*v2) - (mv[5]*v3 - mv[3]*v5);
    Cv[5] = -(mv[0]*v1 - mv[1]*v0) - (mv[3]*v4 - mv[4]*v3);

    // restoring (only row 2 of rot enters)
    const float fb0 = r20*fgz, fb1 = r21*fgz, fb2 = r22*fgz;
    const float bb0 = r20*fbz, bb1 = r21*fbz, bb2 = r22*fbz;
    const float cgx = cgcb[0], cgy = cgcb[1], cgz = cgcb[2];
    const float cbx = cgcb[3], cby = cgcb[4], cbz = cgcb[5];
    const float m0 = cgy*fb2 - cgz*fb1 + cby*bb2 - cbz*bb1;
    const float m1 = cgz*fb0 - cgx*fb2 + cbz*bb0 - cbx*bb2;
    const float m2 = cgx*fb1 - cgy*fb0 + cbx*bb1 - cby*bb0;
    const float g[6] = { -(fb0+bb0), -(fb1+bb1), -(fb2+bb2), -m0, -m1, -m2 };

    float rhs[6];
#pragma unroll
    for (int i = 0; i < 6; ++i) rhs[i] = U[i] - Cv[i] + P[i] - g[i];

    // vDot = Minv @ rhs  (Minv rows broadcast from LDS as b128+b64; values
    // die immediately after their 6 FMAs -> zero VGPR residency)
#pragma unroll
    for (int i = 0; i < 6; ++i) {
        const float4 m4 = *(const float4*)(&smi[i*8]);
        const float2 m2 = *(const float2*)(&smi[i*8 + 4]);
        xd[7+i] = m4.x*rhs[0] + m4.y*rhs[1] + m4.z*rhs[2] + m4.w*rhs[3]
                + m2.x*rhs[4] + m2.y*rhs[5];
    }
}

__global__ void __launch_bounds__(256, 8)
auv_rk2_fused(const float* __restrict__ x, const float* __restrict__ u,
              const float* __restrict__ mass, const float* __restrict__ volume,
              const float* __restrict__ cog, const float* __restrict__ cob,
              const float* __restrict__ mTot, const float* __restrict__ linDamp,
              const float* __restrict__ linDampFow,
              const float* __restrict__ quadDamp,
              float* __restrict__ out, int K)
{
    __shared__ float sx[256 * 13];     // 13312 B, packed rows of 13 floats
    __shared__ float smi[48];          // inv(mTot), rows padded to 8 floats
    const int tid   = threadIdx.x;
    const int w     = tid >> 6;        // wave id (0..3)
    const int l     = tid & 63;        // lane id
    const int wbase = w * 208;         // wave-own float4 region [wbase, wbase+208)
    const int base  = blockIdx.x * 256;
    const int nElem = min(256, K - base);

    // ---- async global->LDS staging, wave-self-contained regions ----
    // wave w loads exactly the float4s backing its own rows [64w, 64w+64):
    // floats [832w, 832w+832) = float4 [208w, 208w+208). LDS dest per issue
    // is uniform-base + lane*16 (HW constraint) -- satisfied by k=wbase+it*64+l.
    if (nElem == 256) {
        const float* gx = x + (size_t)base * 13;
#pragma unroll
        for (int it = 0; it < 3; ++it) {
            const int k = wbase + it*64 + l;
            __builtin_amdgcn_global_load_lds(
                (const __attribute__((address_space(1))) void*)(gx + (size_t)k*4),
                (__attribute__((address_space(3))) void*)(&sx[k*4]), 16, 0, 0);
        }
        if (l < 16) {
            const int k = wbase + 192 + l;
            __builtin_amdgcn_global_load_lds(
                (const __attribute__((address_space(1))) void*)(gx + (size_t)k*4),
                (__attribute__((address_space(3))) void*)(&sx[k*4]), 16, 0, 0);
        }
    } else {
        for (int k = tid; k < nElem*13; k += 256) sx[k] = x[(size_t)base*13 + k];
    }

    // u direct: 3x float2 per thread (overlaps the in-flight LDS DMA)
    float U[6];
    if (tid < nElem) {
        const float* gu = u + (size_t)(base + tid) * 6;
        const float2 a2 = *(const float2*)(gu);
        const float2 b2 = *(const float2*)(gu + 2);
        const float2 c2 = *(const float2*)(gu + 4);
        U[0]=a2.x; U[1]=a2.y; U[2]=b2.x; U[3]=b2.y; U[4]=c2.x; U[5]=c2.y;
    }

    // ---- uniform constants + structure flags (s_load/s_cmp, overlap DMA) ----
    float qdiag[6], lddiag[6], cgcb[6];
#pragma unroll
    for (int i = 0; i < 6; ++i) { qdiag[i] = quadDamp[i*6+i]; lddiag[i] = linDamp[i*6+i]; }
#pragma unroll
    for (int i = 0; i < 3; ++i) { cgcb[i] = cog[i]; cgcb[3+i] = cob[i]; }
    const float fgz = -mass[0] * 9.81f;
    const float fbz =  volume[0] * 1028.0f * 9.81f;

    bool ldDiag = true, ldfZero = true;
#pragma unroll
    for (int i = 0; i < 6; ++i)
#pragma unroll
        for (int j = 0; j < 6; ++j) {
            ldfZero = ldfZero && (linDampFow[i*6+j] == 0.0f);
            if (i != j) ldDiag = ldDiag && (linDamp[i*6+j] == 0.0f);
        }

    // inv(mTot): lane 0 only -> LDS (rows padded to 8). Fully-unrolled
    // static-index fp32 Gauss-Jordan, no pivot (mTot diag-dominant; validated
    // vs reference in the prior session). ~440 serial VALU ops on one lane,
    // fully overlapped with the block's DMA latency.
    if (tid == 0) {
        float a[36], Mi[36];
#pragma unroll
        for (int i = 0; i < 36; ++i) a[i] = mTot[i];
#pragma unroll
        for (int i = 0; i < 36; ++i) Mi[i] = 0.f;
#pragma unroll
        for (int i = 0; i < 6; ++i) Mi[i*6 + i] = 1.f;
#pragma unroll
        for (int col = 0; col < 6; ++col) {
            const float d = fast_rcp(a[col*6 + col]);
#pragma unroll
            for (int j = 0; j < 6; ++j) { a[col*6+j] *= d; Mi[col*6+j] *= d; }
#pragma unroll
            for (int r = 0; r < 6; ++r) {
                if (r == col) continue;
                const float f = a[r*6 + col];
#pragma unroll
                for (int j = 0; j < 6; ++j) {
                    a[r*6+j]  -= f * a[col*6+j];
                    Mi[r*6+j] -= f * Mi[col*6+j];
                }
            }
        }
#pragma unroll
        for (int r = 0; r < 6; ++r)
#pragma unroll
            for (int c = 0; c < 6; ++c) smi[r*8 + c] = Mi[r*6 + c];
    }

    __syncthreads();   // the ONLY block barrier: drains DMA + smi visibility

    if (nElem == 256) {
        float X[13];
#pragma unroll
        for (int j = 0; j < 13; ++j) X[j] = sx[tid*13 + j];

        float k1[13], X2[13], k2[13], Y[13];
        fossen_dot(X, U, smi, mTot, linDamp, linDampFow, qdiag, lddiag, cgcb,
                   fgz, fbz, ldDiag, ldfZero, k1);
#pragma unroll
        for (int j = 0; j < 13; ++j) X2[j] = X[j] + 0.1f * k1[j];
        fossen_dot(X2, U, smi, mTot, linDamp, linDampFow, qdiag, lddiag, cgcb,
                   fgz, fbz, ldDiag, ldfZero, k2);
#pragma unroll
        for (int j = 0; j < 13; ++j) Y[j] = X[j] + 0.05f * (k1[j] + k2[j]);

        const float nq  = Y[3]*Y[3] + Y[4]*Y[4] + Y[5]*Y[5] + Y[6]*Y[6];
        float inv = __builtin_amdgcn_rsqf(nq);
        inv = inv * (1.5f - 0.5f * nq * inv * inv);   // 1 NR step
        Y[3] *= inv; Y[4] *= inv; Y[5] *= inv; Y[6] *= inv;

        // own-row write-back, then wave-LOCAL readback: no block barrier,
        // just drain this wave's LDS ops before re-reading its own region.
#pragma unroll
        for (int j = 0; j < 13; ++j) sx[tid*13 + j] = Y[j];

        asm volatile("s_waitcnt lgkmcnt(0)" ::: "memory");

        float4*       go = (float4*)(out + (size_t)base * 13);
        const float4* s4 = (const float4*)sx;
#pragma unroll
        for (int it = 0; it < 3; ++it) {
            const int k = wbase + it*64 + l;
            go[k] = s4[k];
        }
        if (l < 16) {
            const int k = wbase + 192 + l;
            go[k] = s4[k];
        }
    } else {
        if (tid < nElem) {
            float X[13];
#pragma unroll
            for (int j = 0; j < 13; ++j) X[j] = sx[tid*13 + j];

            float k1[13], X2[13], k2[13], Y[13];
            fossen_dot(X, U, smi, mTot, linDamp, linDampFow, qdiag, lddiag, cgcb,
                       fgz, fbz, ldDiag, ldfZero, k1);
#pragma unroll
            for (int j = 0; j < 13; ++j) X2[j] = X[j] + 0.1f * k1[j];
            fossen_dot(X2, U, smi, mTot, linDamp, linDampFow, qdiag, lddiag, cgcb,
                       fgz, fbz, ldDiag, ldfZero, k2);
#pragma unroll
            for (int j = 0; j < 13; ++j) Y[j] = X[j] + 0.05f * (k1[j] + k2[j]);

            const float nq  = Y[3]*Y[3] + Y[4]*Y[4] + Y[5]*Y[5] + Y[6]*Y[6];
            float inv = __builtin_amdgcn_rsqf(nq);
            inv = inv * (1.5f - 0.5f * nq * inv * inv);
            Y[3] *= inv; Y[4] *= inv; Y[5] *= inv; Y[6] *= inv;
#pragma unroll
            for (int j = 0; j < 13; ++j) sx[tid*13 + j] = Y[j];
        }
        __syncthreads();
        for (int k = tid; k < nElem*13; k += 256) out[(size_t)base*13 + k] = sx[k];
    }
}

extern "C" void kernel_launch(void* const* d_in, const int* in_sizes, int n_in,
                              void* d_out, int out_size, void* d_ws, size_t ws_size,
                              hipStream_t stream)
{
    const float* x          = (const float*)d_in[0];
    const float* u          = (const float*)d_in[1];
    const float* mass       = (const float*)d_in[2];
    const float* volume     = (const float*)d_in[3];
    const float* cog        = (const float*)d_in[4];
    const float* cob        = (const float*)d_in[5];
    const float* mTot       = (const float*)d_in[6];
    const float* linDamp    = (const float*)d_in[7];
    const float* linDampFow = (const float*)d_in[8];
    const float* quadDamp   = (const float*)d_in[9];
    float*       out        = (float*)d_out;

    const int K = in_sizes[0] / 13;
    const int blocks = (K + 255) / 256;
    auv_rk2_fused<<<blocks, 256, 0, stream>>>(x, u, mass, volume, cog, cob,
                                              mTot, linDamp, linDampFow,
                                              quadDamp, out, K);
}

// Round 3
// 118.721 us; speedup vs baseline: 1.5850x; 1.5850x over previous
//
#include <hip/hip_runtime.h>
#include <math.h>

// ---------------------------------------------------------------------------
// AUV Fossen 6-DOF RK2 step, K independent 13-float states.
// R3: R2's (256,8) bound forced 32 VGPR -> ~300MB scratch spill traffic
// (hbm_bytes 79->378MB), kernel 103us. Reverted to proven (256,4) [R1: 64
// VGPR, no spill]. R1's real limiter was phase lockstep (whole grid = one
// resident generation, block-wide barriers sync stage/compute/store ->
// hbm 1.85 TB/s @ occ 31%). R3 removes ALL barriers: each wave owns its 64
// rows end-to-end (own LDS region, own lane-0 GJ inverse into smi[w],
// wave-local s_waitcnt instead of __syncthreads) so 32 waves/CU pipeline
// phases independently. R2's spill run proved the chip sustains 3.7+ TB/s
// at high occupancy. Floor: 79MB -> 12.6us; target 16-20us overlapped.
// ---------------------------------------------------------------------------

__device__ __forceinline__ float fast_rcp(float x) {
    float r = __builtin_amdgcn_rcpf(x);
    return r * (2.0f - x * r);        // 1 Newton step
}

__device__ __forceinline__ void fossen_dot(const float* __restrict__ X,
                                           const float* __restrict__ U,
                                           const float* __restrict__ smi,  // LDS [6][8] padded, broadcast
                                           const float* __restrict__ mTot, // uniform -> s_load
                                           const float* __restrict__ linDamp,
                                           const float* __restrict__ linDampFow,
                                           const float* __restrict__ qdiag,  // sgpr [6]
                                           const float* __restrict__ lddiag, // sgpr [6]
                                           const float* __restrict__ cgcb,   // sgpr [6]
                                           float fgz, float fbz,
                                           bool ldDiag, bool ldfZero,
                                           float* __restrict__ xd)
{
    const float qx = X[3], qy = X[4], qz = X[5], qw = X[6];
    const float r00 = 1.f - 2.f*(qy*qy + qz*qz);
    const float r01 = 2.f*(qx*qy - qz*qw);
    const float r02 = 2.f*(qx*qz + qy*qw);
    const float r10 = 2.f*(qx*qy + qz*qw);
    const float r11 = 1.f - 2.f*(qx*qx + qz*qz);
    const float r12 = 2.f*(qy*qz - qx*qw);
    const float r20 = 2.f*(qx*qz - qy*qw);
    const float r21 = 2.f*(qy*qz + qx*qw);
    const float r22 = 1.f - 2.f*(qx*qx + qy*qy);

    const float v0 = X[7],  v1 = X[8],  v2 = X[9];
    const float v3 = X[10], v4 = X[11], v5 = X[12];

    xd[0] = r00*v0 + r01*v1 + r02*v2;
    xd[1] = r10*v0 + r11*v1 + r12*v2;
    xd[2] = r20*v0 + r21*v1 + r22*v2;
    xd[3] = 0.5f*(-qx*v3 - qy*v4 - qz*v5);
    xd[4] = 0.5f*( qw*v3 - qz*v4 + qy*v5);
    xd[5] = 0.5f*( qz*v3 + qw*v4 - qx*v5);
    xd[6] = 0.5f*(-qy*v3 + qx*v4 + qw*v5);

    const float v[6] = {v0, v1, v2, v3, v4, v5};

    // P = -Dv. Fast path: diagonal linDamp + zero linDampFow (uniform flags).
    float P[6];
#pragma unroll
    for (int i = 0; i < 6; ++i)
        P[i] = lddiag[i]*v[i] + qdiag[i]*fabsf(v[i])*v[i];
    if (!ldDiag) {
#pragma unroll
        for (int i = 0; i < 6; ++i) {
            float ld = 0.f;
#pragma unroll
            for (int j = 0; j < 6; ++j)
                if (j != i) ld += linDamp[i*6 + j] * v[j];
            P[i] += ld;
        }
    }
    if (!ldfZero) {
#pragma unroll
        for (int i = 0; i < 6; ++i) {
            float ldf = 0.f;
#pragma unroll
            for (int j = 0; j < 6; ++j) ldf += linDampFow[i*6 + j] * v[j];
            P[i] += v[i]*ldf;
        }
    }

    // Coriolis via mv = M v, then cross products (skew(a)b = a x b)
    float mv[6];
#pragma unroll
    for (int i = 0; i < 6; ++i) {
        float s = 0.f;
#pragma unroll
        for (int j = 0; j < 6; ++j) s += mTot[i*6 + j] * v[j];
        mv[i] = s;
    }
    float Cv[6];
    Cv[0] = -(mv[1]*v5 - mv[2]*v4);
    Cv[1] = -(mv[2]*v3 - mv[0]*v5);
    Cv[2] = -(mv[0]*v4 - mv[1]*v3);
    Cv[3] = -(mv[1]*v2 - mv[2]*v1) - (mv[4]*v5 - mv[5]*v4);
    Cv[4] = -(mv[2]*v0 - mv[0]*v2) - (mv[5]*v3 - mv[3]*v5);
    Cv[5] = -(mv[0]*v1 - mv[1]*v0) - (mv[3]*v4 - mv[4]*v3);

    // restoring (only row 2 of rot enters)
    const float fb0 = r20*fgz, fb1 = r21*fgz, fb2 = r22*fgz;
    const float bb0 = r20*fbz, bb1 = r21*fbz, bb2 = r22*fbz;
    const float cgx = cgcb[0], cgy = cgcb[1], cgz = cgcb[2];
    const float cbx = cgcb[3], cby = cgcb[4], cbz = cgcb[5];
    const float m0 = cgy*fb2 - cgz*fb1 + cby*bb2 - cbz*bb1;
    const float m1 = cgz*fb0 - cgx*fb2 + cbz*bb0 - cbx*bb2;
    const float m2 = cgx*fb1 - cgy*fb0 + cbx*bb1 - cby*bb0;
    const float g[6] = { -(fb0+bb0), -(fb1+bb1), -(fb2+bb2), -m0, -m1, -m2 };

    float rhs[6];
#pragma unroll
    for (int i = 0; i < 6; ++i) rhs[i] = U[i] - Cv[i] + P[i] - g[i];

    // vDot = Minv @ rhs  (rows broadcast from LDS as b128+b64, die after use)
#pragma unroll
    for (int i = 0; i < 6; ++i) {
        const float4 m4 = *(const float4*)(&smi[i*8]);
        const float2 m2 = *(const float2*)(&smi[i*8 + 4]);
        xd[7+i] = m4.x*rhs[0] + m4.y*rhs[1] + m4.z*rhs[2] + m4.w*rhs[3]
                + m2.x*rhs[4] + m2.y*rhs[5];
    }
}

// lane-0 Gauss-Jordan (static-index, no pivot; mTot diag-dominant, validated
// vs reference) into this wave's padded smi region.
__device__ __forceinline__ void gj_inverse_to_lds(const float* __restrict__ mTot,
                                                  float* __restrict__ smiw)
{
    float a[36], Mi[36];
#pragma unroll
    for (int i = 0; i < 36; ++i) a[i] = mTot[i];
#pragma unroll
    for (int i = 0; i < 36; ++i) Mi[i] = 0.f;
#pragma unroll
    for (int i = 0; i < 6; ++i) Mi[i*6 + i] = 1.f;
#pragma unroll
    for (int col = 0; col < 6; ++col) {
        const float d = fast_rcp(a[col*6 + col]);
#pragma unroll
        for (int j = 0; j < 6; ++j) { a[col*6+j] *= d; Mi[col*6+j] *= d; }
#pragma unroll
        for (int r = 0; r < 6; ++r) {
            if (r == col) continue;
            const float f = a[r*6 + col];
#pragma unroll
            for (int j = 0; j < 6; ++j) {
                a[r*6+j]  -= f * a[col*6+j];
                Mi[r*6+j] -= f * Mi[col*6+j];
            }
        }
    }
#pragma unroll
    for (int r = 0; r < 6; ++r)
#pragma unroll
        for (int c = 0; c < 6; ++c) smiw[r*8 + c] = Mi[r*6 + c];
}

__global__ void __launch_bounds__(256, 4)
auv_rk2_fused(const float* __restrict__ x, const float* __restrict__ u,
              const float* __restrict__ mass, const float* __restrict__ volume,
              const float* __restrict__ cog, const float* __restrict__ cob,
              const float* __restrict__ mTot, const float* __restrict__ linDamp,
              const float* __restrict__ linDampFow,
              const float* __restrict__ quadDamp,
              float* __restrict__ out, int K)
{
    __shared__ float sx[256 * 13];     // 13312 B, packed rows of 13 floats
    __shared__ float smi[4][48];       // per-WAVE inv(mTot), rows padded to 8
    const int tid   = threadIdx.x;
    const int w     = tid >> 6;        // wave id (0..3)
    const int l     = tid & 63;        // lane id
    const int wf4   = w * 208;         // wave-own float4 region [wf4, wf4+208)
    const int base  = blockIdx.x * 256;
    const int nElem = min(256, K - base);

    // ---- uniform constants + structure flags (s_load/SALU) ----
    float qdiag[6], lddiag[6], cgcb[6];
#pragma unroll
    for (int i = 0; i < 6; ++i) { qdiag[i] = quadDamp[i*6+i]; lddiag[i] = linDamp[i*6+i]; }
#pragma unroll
    for (int i = 0; i < 3; ++i) { cgcb[i] = cog[i]; cgcb[3+i] = cob[i]; }
    const float fgz = -mass[0] * 9.81f;
    const float fbz =  volume[0] * 1028.0f * 9.81f;

    bool ldDiag = true, ldfZero = true;
#pragma unroll
    for (int i = 0; i < 6; ++i)
#pragma unroll
        for (int j = 0; j < 6; ++j) {
            ldfZero = ldfZero && (linDampFow[i*6+j] == 0.0f);
            if (i != j) ldDiag = ldDiag && (linDamp[i*6+j] == 0.0f);
        }

    if (nElem == 256) {
        // ================== wave-independent fast path, NO barriers =========
        // 1) issue this wave's global->LDS DMA (wave-uniform LDS base + l*16)
        const float* gx = x + (size_t)base * 13;
#pragma unroll
        for (int it = 0; it < 3; ++it) {
            const int k = wf4 + it*64 + l;
            __builtin_amdgcn_global_load_lds(
                (const __attribute__((address_space(1))) void*)(gx + (size_t)k*4),
                (__attribute__((address_space(3))) void*)(&sx[k*4]), 16, 0, 0);
        }
        if (l < 16) {
            const int k = wf4 + 192 + l;
            __builtin_amdgcn_global_load_lds(
                (const __attribute__((address_space(1))) void*)(gx + (size_t)k*4),
                (__attribute__((address_space(3))) void*)(&sx[k*4]), 16, 0, 0);
        }

        // 2) u direct (overlaps the in-flight DMA)
        float U[6];
        {
            const float* gu = u + (size_t)(base + tid) * 6;
            const float2 a2 = *(const float2*)(gu);
            const float2 b2 = *(const float2*)(gu + 2);
            const float2 c2 = *(const float2*)(gu + 4);
            U[0]=a2.x; U[1]=a2.y; U[2]=b2.x; U[3]=b2.y; U[4]=c2.x; U[5]=c2.y;
        }

        // 3) per-wave lane-0 inverse into smi[w] (overlaps DMA latency)
        if (l == 0) gj_inverse_to_lds(mTot, &smi[w][0]);

        // 4) wave-LOCAL drain: this wave's DMA + lane-0 ds_writes. No barrier.
        asm volatile("s_waitcnt vmcnt(0) lgkmcnt(0)" ::: "memory");

        // 5) compute
        float X[13];
#pragma unroll
        for (int j = 0; j < 13; ++j) X[j] = sx[tid*13 + j];

        float k1[13], X2[13], k2[13], Y[13];
        fossen_dot(X, U, &smi[w][0], mTot, linDamp, linDampFow, qdiag, lddiag,
                   cgcb, fgz, fbz, ldDiag, ldfZero, k1);
#pragma unroll
        for (int j = 0; j < 13; ++j) X2[j] = X[j] + 0.1f * k1[j];
        fossen_dot(X2, U, &smi[w][0], mTot, linDamp, linDampFow, qdiag, lddiag,
                   cgcb, fgz, fbz, ldDiag, ldfZero, k2);
#pragma unroll
        for (int j = 0; j < 13; ++j) Y[j] = X[j] + 0.05f * (k1[j] + k2[j]);

        const float nq  = Y[3]*Y[3] + Y[4]*Y[4] + Y[5]*Y[5] + Y[6]*Y[6];
        float inv = __builtin_amdgcn_rsqf(nq);
        inv = inv * (1.5f - 0.5f * nq * inv * inv);   // 1 NR step
        Y[3] *= inv; Y[4] *= inv; Y[5] *= inv; Y[6] *= inv;

        // 6) own-row write-back, wave-local drain, coalesced store of own region
#pragma unroll
        for (int j = 0; j < 13; ++j) sx[tid*13 + j] = Y[j];

        asm volatile("s_waitcnt lgkmcnt(0)" ::: "memory");

        float4*       go = (float4*)(out + (size_t)base * 13);
        const float4* s4 = (const float4*)sx;
#pragma unroll
        for (int it = 0; it < 3; ++it) {
            const int k = wf4 + it*64 + l;
            go[k] = s4[k];
        }
        if (l < 16) {
            const int k = wf4 + 192 + l;
            go[k] = s4[k];
        }
    } else {
        // ================== tail path (block-uniform branch, barriers OK) ===
        for (int k = tid; k < nElem*13; k += 256) sx[k] = x[(size_t)base*13 + k];

        float U[6] = {0,0,0,0,0,0};
        if (tid < nElem) {
            const float* gu = u + (size_t)(base + tid) * 6;
            const float2 a2 = *(const float2*)(gu);
            const float2 b2 = *(const float2*)(gu + 2);
            const float2 c2 = *(const float2*)(gu + 4);
            U[0]=a2.x; U[1]=a2.y; U[2]=b2.x; U[3]=b2.y; U[4]=c2.x; U[5]=c2.y;
        }
        if (tid == 0) gj_inverse_to_lds(mTot, &smi[0][0]);
        __syncthreads();

        if (tid < nElem) {
            float X[13];
#pragma unroll
            for (int j = 0; j < 13; ++j) X[j] = sx[tid*13 + j];

            float k1[13], X2[13], k2[13], Y[13];
            fossen_dot(X, U, &smi[0][0], mTot, linDamp, linDampFow, qdiag,
                       lddiag, cgcb, fgz, fbz, ldDiag, ldfZero, k1);
#pragma unroll
            for (int j = 0; j < 13; ++j) X2[j] = X[j] + 0.1f * k1[j];
            fossen_dot(X2, U, &smi[0][0], mTot, linDamp, linDampFow, qdiag,
                       lddiag, cgcb, fgz, fbz, ldDiag, ldfZero, k2);
#pragma unroll
            for (int j = 0; j < 13; ++j) Y[j] = X[j] + 0.05f * (k1[j] + k2[j]);

            const float nq  = Y[3]*Y[3] + Y[4]*Y[4] + Y[5]*Y[5] + Y[6]*Y[6];
            float inv = __builtin_amdgcn_rsqf(nq);
            inv = inv * (1.5f - 0.5f * nq * inv * inv);
            Y[3] *= inv; Y[4] *= inv; Y[5] *= inv; Y[6] *= inv;
#pragma unroll
            for (int j = 0; j < 13; ++j) sx[tid*13 + j] = Y[j];
        }
        __syncthreads();
        for (int k = tid; k < nElem*13; k += 256) out[(size_t)base*13 + k] = sx[k];
    }
}

extern "C" void kernel_launch(void* const* d_in, const int* in_sizes, int n_in,
                              void* d_out, int out_size, void* d_ws, size_t ws_size,
                              hipStream_t stream)
{
    const float* x          = (const float*)d_in[0];
    const float* u          = (const float*)d_in[1];
    const float* mass       = (const float*)d_in[2];
    const float* volume     = (const float*)d_in[3];
    const float* cog        = (const float*)d_in[4];
    const float* cob        = (const float*)d_in[5];
    const float* mTot       = (const float*)d_in[6];
    const float* linDamp    = (const float*)d_in[7];
    const float* linDampFow = (const float*)d_in[8];
    const float* quadDamp   = (const float*)d_in[9];
    float*       out        = (float*)d_out;

    const int K = in_sizes[0] / 13;
    const int blocks = (K + 255) / 256;
    auv_rk2_fused<<<blocks, 256, 0, stream>>>(x, u, mass, volume, cog, cob,
                                              mTot, linDamp, linDampFow,
                                              quadDamp, out, K);
}